// Round 12
// baseline (2010.283 us; speedup 1.0000x reference)
//
#include <hip/hip_runtime.h>
#include <math.h>

#define NNODES 5000
#define NEDGES 50000
#define SEQT 12
#define NB 40000
#define MAXDEG 128

typedef __attribute__((ext_vector_type(8))) _Float16 half8;
typedef __attribute__((ext_vector_type(2))) _Float16 half2v;
typedef __attribute__((ext_vector_type(4))) float f32x4;

// ---------------- setup kernels ----------------

__global__ void count_deg_k(const int* __restrict__ ei, int* deg_out, int* deg_in){
    int e = blockIdx.x*blockDim.x + threadIdx.x;
    if (e < NEDGES){
        atomicAdd(&deg_out[ei[e]], 1);
        atomicAdd(&deg_in[ei[NEDGES + e]], 1);
    }
}

__global__ void scan_k(const int* __restrict__ deg_in, int* __restrict__ row_ptr){
    __shared__ int part[256];
    int tid = threadIdx.x;
    int base = tid*20;
    int loc[20]; int s = 0;
    for (int i=0;i<20;i++){
        int idx = base+i;
        int v = (idx < NNODES) ? deg_in[idx] : 0;
        loc[i] = s; s += v;
    }
    part[tid] = s;
    __syncthreads();
    for (int off=1; off<256; off<<=1){
        int v = (tid>=off) ? part[tid-off] : 0;
        __syncthreads();
        part[tid] += v;
        __syncthreads();
    }
    int prev = (tid==0) ? 0 : part[tid-1];
    for (int i=0;i<20;i++){
        int idx = base+i;
        if (idx < NNODES) row_ptr[idx] = prev + loc[i];
    }
    if (tid==255) row_ptr[NNODES] = part[255];
}

__global__ void fill_csr_k(const int* __restrict__ ei, const int* __restrict__ deg_out,
                           const int* __restrict__ deg_in, const int* __restrict__ row_ptr,
                           int* cursor, int* __restrict__ csr_src,
                           float* __restrict__ csr_wo, float* __restrict__ csr_wi){
    int e = blockIdx.x*blockDim.x + threadIdx.x;
    if (e >= NEDGES) return;
    int s = ei[e], d = ei[NEDGES+e];
    int pos = atomicAdd(&cursor[d], 1);
    int slot = row_ptr[d] + pos;
    csr_src[slot] = s;
    csr_wo[slot] = 1.f/(float)deg_out[s];
    csr_wi[slot] = 1.f/(float)deg_in[d];
}

// pre-pack x for all timesteps: Xtph[t][row][2] fp16, row = n*8+b
__global__ void prepack_x_k(const float* __restrict__ x, _Float16* __restrict__ Xtph){
    int idx = blockIdx.x*256 + threadIdx.x;
    if (idx >= SEQT*NB*2) return;
    int tt = idx / (NB*2);
    int r2 = idx - tt*(NB*2);
    int row = r2 >> 1, f = r2 & 1;
    int n = row >> 3, b = row & 7;
    Xtph[idx] = (_Float16)x[((size_t)(b*SEQT+tt)*NNODES + n)*2 + f];
}

// ---------------- weight packing (refolded basis, fp16, ks-major MFMA B-frag) ----------------
__device__ __forceinline__ float wfetch(const float* __restrict__ W, int F, int slot, int f, int c){
    const float* p0 = W + ((size_t)0*F + f)*64 + c;
    const float* p1 = W + ((size_t)1*F + f)*64 + c;
    const float* p2 = W + ((size_t)2*F + f)*64 + c;
    const float* p3 = W + ((size_t)3*F + f)*64 + c;
    const float* p4 = W + ((size_t)4*F + f)*64 + c;
    const float* p5 = W + ((size_t)5*F + f)*64 + c;
    switch(slot){
        case 0: return *p0 + *p3 - *p2 - *p5;
        case 1: return *p1;
        case 2: return *p4;
        case 3: return 2.f * *p2;
        default: return 2.f * *p5;
    }
}

__global__ void pack_l0_k(const float* __restrict__ W, _Float16* __restrict__ wh){
    int idx = blockIdx.x*256 + threadIdx.x;
    if (idx >= 4*11*64) return;
    int lane = idx & 63, rest = idx >> 6;
    int ks = rest % 11, cf = rest / 11;
    int col = cf*16 + (lane & 15);
    int kb = ks*32 + ((lane>>4)<<3);
    size_t o = ((size_t)(ks*4 + cf)*64 + lane)*8;
    for (int j=0;j<8;j++){
        int k = kb + j;
        float v = 0.f;
        if (ks == 0){
            if (k < 10) v = wfetch(W, 66, k>>1, k&1, col);
        } else {
            int slot = (ks-1)>>1;
            int f = 2 + k - 32 - 64*slot;
            v = wfetch(W, 66, slot, f, col);
        }
        wh[o+j] = (_Float16)v;
    }
}

__global__ void pack_l1_k(const float* __restrict__ W, _Float16* __restrict__ wh){
    int idx = blockIdx.x*256 + threadIdx.x;
    if (idx >= 4*20*64) return;
    int lane = idx & 63, rest = idx >> 6;
    int ks = rest % 20, cf = rest / 20;
    int col = cf*16 + (lane & 15);
    int kb = ks*32 + ((lane>>4)<<3);
    int slot = ks >> 2;
    size_t o = ((size_t)(ks*4 + cf)*64 + lane)*8;
    for (int j=0;j<8;j++){
        int k = kb + j;
        int f = k - slot*128;
        wh[o+j] = (_Float16)wfetch(W, 128, slot, f, col);
    }
}

// ---------------- fused pipelined stage kernels ----------------
// Iteration s fuses: A = L1 stage of timestep s, B = L0 stage of timestep s+1.
// h0-derived props (Th1*, Th2*) are shared between L0(s+1) and L1(s) — computed once (B-half).

// F1: A = dual prop of h1h -> T1o64/T1i64; B = dual prop of h0h -> Th1o/Th1i + x side-channel
__global__ __launch_bounds__(64) void k_f1(int aCount,
    const _Float16* __restrict__ h0h, const _Float16* __restrict__ h1h,
    _Float16* __restrict__ T1o64, _Float16* __restrict__ T1i64,
    const _Float16* __restrict__ Xt,
    _Float16* __restrict__ Th1o, _Float16* __restrict__ Th1i, _Float16* __restrict__ XTh,
    const int* __restrict__ rp, const int* __restrict__ cs,
    const float* __restrict__ cwo, const float* __restrict__ cwi){
    __shared__ int s_o[MAXDEG]; __shared__ float swo[MAXDEG], swi[MAXDEG];
    const int bx = blockIdx.x;
    const bool isA = bx < aCount;
    const int n = isA ? bx : bx - aCount;
    int beg = rp[n], deg = rp[n+1]-beg;
    int nst = deg < MAXDEG ? deg : MAXDEG;
    for (int j=threadIdx.x; j<nst; j+=64){
        s_o[j] = cs[beg+j]*512;
        swo[j] = cwo[beg+j]; swi[j] = cwi[beg+j];
    }
    __syncthreads();
    const _Float16* S = isA ? h1h : h0h;
    _Float16* Yo = isA ? T1o64 : Th1o;
    _Float16* Yi = isA ? T1i64 : Th1i;
    int off = threadIdx.x*8;
    {
        float ao[8] = {0,0,0,0,0,0,0,0}, ai[8] = {0,0,0,0,0,0,0,0};
        for (int j=0;j<nst;j++){
            half8 v = *(const half8*)(S + s_o[j] + off);
            float wo=swo[j], wi=swi[j];
            #pragma unroll
            for (int e=0;e<8;e++){
                float xv = (float)v[e];
                ao[e]=fmaf(wo,xv,ao[e]); ai[e]=fmaf(wi,xv,ai[e]);
            }
        }
        for (int j=nst;j<deg;j++){
            half8 v = *(const half8*)(S + (size_t)cs[beg+j]*512 + off);
            float wo=cwo[beg+j], wi=cwi[beg+j];
            #pragma unroll
            for (int e=0;e<8;e++){
                float xv = (float)v[e];
                ao[e]=fmaf(wo,xv,ao[e]); ai[e]=fmaf(wi,xv,ai[e]);
            }
        }
        half8 po, pi;
        #pragma unroll
        for (int e=0;e<8;e++){ po[e]=(_Float16)ao[e]; pi[e]=(_Float16)ai[e]; }
        *(half8*)(Yo + (size_t)n*512 + off) = po;
        *(half8*)(Yi + (size_t)n*512 + off) = pi;
    }
    if (!isA && threadIdx.x < 8){
        int b = threadIdx.x;
        float ax0=0,ax1=0, ay0=0,ay1=0;
        for (int j=0;j<nst;j++){
            int src = s_o[j] >> 9;
            half2v v = *(const half2v*)(Xt + src*16 + b*2);
            float x0=(float)v[0], x1=(float)v[1];
            ax0=fmaf(swo[j],x0,ax0); ax1=fmaf(swo[j],x1,ax1);
            ay0=fmaf(swi[j],x0,ay0); ay1=fmaf(swi[j],x1,ay1);
        }
        for (int j=nst;j<deg;j++){
            int src = cs[beg+j];
            half2v v = *(const half2v*)(Xt + src*16 + b*2);
            float x0=(float)v[0], x1=(float)v[1];
            ax0=fmaf(cwo[beg+j],x0,ax0); ax1=fmaf(cwo[beg+j],x1,ax1);
            ay0=fmaf(cwi[beg+j],x0,ay0); ay1=fmaf(cwi[beg+j],x1,ay1);
        }
        size_t ro = (size_t)(n*8 + b)*32;
        XTh[ro+0] = Xt[(size_t)(n*8+b)*2+0];
        XTh[ro+1] = Xt[(size_t)(n*8+b)*2+1];
        XTh[ro+2] = (_Float16)ax0; XTh[ro+3] = (_Float16)ax1;
        XTh[ro+4] = (_Float16)ay0; XTh[ro+5] = (_Float16)ay1;
    }
}

// F2: A = single-dir prop T1{o,i}64 -> U2{o,i}64 (2N blocks); B = Th1* -> Th2* + x side-channel (2N blocks)
__global__ __launch_bounds__(64) void k_f2(int aCount,
    const _Float16* __restrict__ T1o64, const _Float16* __restrict__ T1i64,
    _Float16* __restrict__ U2o64, _Float16* __restrict__ U2i64,
    const _Float16* __restrict__ Th1o, const _Float16* __restrict__ Th1i,
    _Float16* __restrict__ Th2o, _Float16* __restrict__ Th2i, _Float16* __restrict__ XTh,
    const int* __restrict__ rp, const int* __restrict__ cs,
    const float* __restrict__ cwo, const float* __restrict__ cwi){
    __shared__ int s_o[MAXDEG]; __shared__ float s_w[MAXDEG];
    const int bx = blockIdx.x;
    const bool isA = bx < aCount;
    const int idx = isA ? bx : bx - aCount;
    const int n = idx >> 1, sel = idx & 1;
    const float* cw = sel ? cwi : cwo;
    int beg = rp[n], deg = rp[n+1]-beg;
    int nst = deg < MAXDEG ? deg : MAXDEG;
    for (int j=threadIdx.x; j<nst; j+=64){
        s_o[j] = cs[beg+j]*512;
        s_w[j] = cw[beg+j];
    }
    __syncthreads();
    const _Float16* S = isA ? (sel ? T1i64 : T1o64) : (sel ? Th1i : Th1o);
    _Float16* U = isA ? (sel ? U2i64 : U2o64) : (sel ? Th2i : Th2o);
    int off = threadIdx.x*8;
    {
        float a[8] = {0,0,0,0,0,0,0,0};
        for (int j=0;j<nst;j++){
            half8 v = *(const half8*)(S + s_o[j] + off);
            float w=s_w[j];
            #pragma unroll
            for (int e=0;e<8;e++) a[e]=fmaf(w,(float)v[e],a[e]);
        }
        for (int j=nst;j<deg;j++){
            half8 v = *(const half8*)(S + (size_t)cs[beg+j]*512 + off);
            float w=cw[beg+j];
            #pragma unroll
            for (int e=0;e<8;e++) a[e]=fmaf(w,(float)v[e],a[e]);
        }
        half8 p;
        #pragma unroll
        for (int e=0;e<8;e++) p[e]=(_Float16)a[e];
        *(half8*)(U + (size_t)n*512 + off) = p;
    }
    if (!isA && threadIdx.x < 8){
        int b = threadIdx.x;
        int xo = 2 + 2*sel;
        float a0=0,a1=0;
        for (int j=0;j<nst;j++){
            int src = s_o[j] >> 9;
            half2v v = *(const half2v*)(XTh + (size_t)src*256 + b*32 + xo);
            a0=fmaf(s_w[j],(float)v[0],a0); a1=fmaf(s_w[j],(float)v[1],a1);
        }
        for (int j=nst;j<deg;j++){
            int src = cs[beg+j];
            float w = cw[beg+j];
            half2v v = *(const half2v*)(XTh + (size_t)src*256 + b*32 + xo);
            a0=fmaf(w,(float)v[0],a0); a1=fmaf(w,(float)v[1],a1);
        }
        size_t ro = (size_t)(n*8 + b)*32 + 6 + 2*sel;
        XTh[ro+0] = (_Float16)a0; XTh[ro+1] = (_Float16)a1;
    }
}

// F4: dual prop of 64-wide G tensors (A and B halves, identical body, ptr select)
__global__ __launch_bounds__(64) void k_f4(int aCount,
    const _Float16* __restrict__ SA, _Float16* __restrict__ YoA, _Float16* __restrict__ YiA,
    const _Float16* __restrict__ SB, _Float16* __restrict__ YoB, _Float16* __restrict__ YiB,
    const int* __restrict__ rp, const int* __restrict__ cs,
    const float* __restrict__ cwo, const float* __restrict__ cwi){
    __shared__ int s_o[MAXDEG]; __shared__ float swo[MAXDEG], swi[MAXDEG];
    const int bx = blockIdx.x;
    const bool isA = bx < aCount;
    const int n = isA ? bx : bx - aCount;
    const _Float16* S = isA ? SA : SB;
    _Float16* Yo = isA ? YoA : YoB;
    _Float16* Yi = isA ? YiA : YiB;
    int beg = rp[n], deg = rp[n+1]-beg;
    int nst = deg < MAXDEG ? deg : MAXDEG;
    for (int j=threadIdx.x; j<nst; j+=64){
        s_o[j] = cs[beg+j]*512;
        swo[j] = cwo[beg+j]; swi[j] = cwi[beg+j];
    }
    __syncthreads();
    int off = threadIdx.x*8;
    float ao[8] = {0,0,0,0,0,0,0,0}, ai[8] = {0,0,0,0,0,0,0,0};
    for (int j=0;j<nst;j++){
        half8 v = *(const half8*)(S + s_o[j] + off);
        float wo=swo[j], wi=swi[j];
        #pragma unroll
        for (int e=0;e<8;e++){
            float xv = (float)v[e];
            ao[e]=fmaf(wo,xv,ao[e]); ai[e]=fmaf(wi,xv,ai[e]);
        }
    }
    for (int j=nst;j<deg;j++){
        half8 v = *(const half8*)(S + (size_t)cs[beg+j]*512 + off);
        float wo=cwo[beg+j], wi=cwi[beg+j];
        #pragma unroll
        for (int e=0;e<8;e++){
            float xv = (float)v[e];
            ao[e]=fmaf(wo,xv,ao[e]); ai[e]=fmaf(wi,xv,ai[e]);
        }
    }
    half8 po, pi;
    #pragma unroll
    for (int e=0;e<8;e++){ po[e]=(_Float16)ao[e]; pi[e]=(_Float16)ai[e]; }
    *(half8*)(Yo + (size_t)n*512 + off) = po;
    *(half8*)(Yi + (size_t)n*512 + off) = pi;
}

// F5: second hop of 64-wide G tensors (A and B halves, sel = idx&1)
__global__ __launch_bounds__(64) void k_f5(int aCount,
    const _Float16* __restrict__ T1oA, const _Float16* __restrict__ T1iA,
    _Float16* __restrict__ U2oA, _Float16* __restrict__ U2iA,
    const _Float16* __restrict__ T1oB, const _Float16* __restrict__ T1iB,
    _Float16* __restrict__ U2oB, _Float16* __restrict__ U2iB,
    const int* __restrict__ rp, const int* __restrict__ cs,
    const float* __restrict__ cwo, const float* __restrict__ cwi){
    __shared__ int s_o[MAXDEG]; __shared__ float s_w[MAXDEG];
    const int bx = blockIdx.x;
    const bool isA = bx < aCount;
    const int idx = isA ? bx : bx - aCount;
    const int n = idx >> 1, sel = idx & 1;
    const _Float16* S = isA ? (sel ? T1iA : T1oA) : (sel ? T1iB : T1oB);
    _Float16* U = isA ? (sel ? U2iA : U2oA) : (sel ? U2iB : U2oB);
    const float* cw = sel ? cwi : cwo;
    int beg = rp[n], deg = rp[n+1]-beg;
    int nst = deg < MAXDEG ? deg : MAXDEG;
    for (int j=threadIdx.x; j<nst; j+=64){
        s_o[j] = cs[beg+j]*512;
        s_w[j] = cw[beg+j];
    }
    __syncthreads();
    int off = threadIdx.x*8;
    float a[8] = {0,0,0,0,0,0,0,0};
    for (int j=0;j<nst;j++){
        half8 v = *(const half8*)(S + s_o[j] + off);
        float w=s_w[j];
        #pragma unroll
        for (int e=0;e<8;e++) a[e]=fmaf(w,(float)v[e],a[e]);
    }
    for (int j=nst;j<deg;j++){
        half8 v = *(const half8*)(S + (size_t)cs[beg+j]*512 + off);
        float w=cw[beg+j];
        #pragma unroll
        for (int e=0;e<8;e++) a[e]=fmaf(w,(float)v[e],a[e]);
    }
    half8 p;
    #pragma unroll
    for (int e=0;e<8;e++) p[e]=(_Float16)a[e];
    *(half8*)(U + (size_t)n*512 + off) = p;
}

// ---------------- MFMA f16 GEMM body: barrier-free, direct L2 B reads ----------------

struct KD { const _Float16* a; int st; };
struct GA { KD kd[20]; };

template<int NK, int NG, int EPI>
__device__ __forceinline__ void gemm_body(float* spr, int bxm, const GA& ga,
    const _Float16* __restrict__ wh0, const float* __restrict__ b0,
    const _Float16* __restrict__ wh1, const float* __restrict__ b1,
    float* __restrict__ Z, _Float16* __restrict__ Gout,
    float* __restrict__ Hf, _Float16* __restrict__ Hh,
    const float* __restrict__ Wo, const float* __restrict__ bo,
    float* __restrict__ out, int t){
    const int tid = threadIdx.x;
    const int lane = tid & 63, wv = tid >> 6, rl = lane & 15, kg = lane >> 4;
    const int m0 = bxm*64 + (wv&1)*32;
    const int cfb = (wv>>1)*2;

    f32x4 acc[NG][2][2];
    #pragma unroll
    for (int g=0; g<NG; ++g)
        #pragma unroll
        for (int cc=0; cc<2; ++cc)
            #pragma unroll
            for (int mr=0; mr<2; ++mr){
                acc[g][cc][mr][0]=0.f; acc[g][cc][mr][1]=0.f;
                acc[g][cc][mr][2]=0.f; acc[g][cc][mr][3]=0.f;
            }

    #pragma unroll
    for (int ks=0; ks<NK; ++ks){
        const _Float16* base = ga.kd[ks].a;
        const int st = ga.kd[ks].st;
        half8 a0 = *(const half8*)(base + (size_t)(m0+rl)*st + kg*8);
        half8 a1 = *(const half8*)(base + (size_t)(m0+16+rl)*st + kg*8);
        #pragma unroll
        for (int g=0; g<NG; ++g){
            const _Float16* ws = g ? wh1 : wh0;
            #pragma unroll
            for (int cc=0; cc<2; ++cc){
                half8 bv = *(const half8*)(ws + (size_t)ks*2048 + (cfb+cc)*512 + lane*8);
                acc[g][cc][0] = __builtin_amdgcn_mfma_f32_16x16x32_f16(a0, bv, acc[g][cc][0], 0, 0, 0);
                acc[g][cc][1] = __builtin_amdgcn_mfma_f32_16x16x32_f16(a1, bv, acc[g][cc][1], 0, 0, 0);
            }
        }
    }

    if constexpr (EPI == 0){
        #pragma unroll
        for (int cc=0; cc<2; ++cc){
            const int col = (cfb+cc)*16 + rl;
            float bzv = b0[col], brv = b1[col];
            #pragma unroll
            for (int mr=0; mr<2; ++mr)
                #pragma unroll
                for (int i=0;i<4;i++){
                    int row = m0 + mr*16 + kg*4 + i;
                    float z = 1.f/(1.f+__expf(-(acc[0][cc][mr][i] + bzv)));
                    float r = 1.f/(1.f+__expf(-(acc[NG-1][cc][mr][i] + brv)));
                    size_t ix = (size_t)row*64 + col;
                    Z[ix] = z;
                    Gout[ix] = (_Float16)(Hf[ix]*r);
                }
        }
    } else {
        float pr[2][4] = {{0.f,0.f,0.f,0.f},{0.f,0.f,0.f,0.f}};
        #pragma unroll
        for (int cc=0; cc<2; ++cc){
            const int col = (cfb+cc)*16 + rl;
            float bv = b0[col];
            float wo_c = 0.f;
            if constexpr (EPI == 2) wo_c = Wo[col];
            #pragma unroll
            for (int mr=0; mr<2; ++mr)
                #pragma unroll
                for (int i=0;i<4;i++){
                    int row = m0 + mr*16 + kg*4 + i;
                    float ht = tanhf(acc[0][cc][mr][i] + bv);
                    size_t ix = (size_t)row*64 + col;
                    float z = Z[ix];
                    float hn = z*Hf[ix] + (1.f-z)*ht;
                    Hf[ix] = hn;
                    Hh[ix] = (_Float16)hn;
                    if constexpr (EPI == 2) pr[mr][i] = fmaf(hn, wo_c, pr[mr][i]);
                }
        }
        if constexpr (EPI == 2){
            #pragma unroll
            for (int mr=0; mr<2; ++mr)
                #pragma unroll
                for (int i=0;i<4;i++){
                    float v = pr[mr][i];
                    v += __shfl_xor(v, 1);
                    v += __shfl_xor(v, 2);
                    v += __shfl_xor(v, 4);
                    v += __shfl_xor(v, 8);
                    if (rl == 0) spr[wv*32 + mr*16 + kg*4 + i] = v;
                }
            __syncthreads();
            if (tid < 64){
                int r = tid;
                float v = spr[(r>>5)*32 + (r&31)] + spr[((r>>5)|2)*32 + (r&31)] + bo[0];
                int row = bxm*64 + r;
                int n = row >> 3, b = row & 7;
                out[(size_t)(b*SEQT + t)*NNODES + n] = v;
            }
        }
    }
}

// F3: A = L1 z/r GEMM (NK=20); B = L0 z/r GEMM (NK=11)
__global__ __launch_bounds__(256) void k_f3(int aCount,
    GA gaA, const _Float16* whA0, const float* bA0, const _Float16* whA1, const float* bA1,
    float* ZA, _Float16* GoA, float* HfA,
    GA gaB, const _Float16* whB0, const float* bB0, const _Float16* whB1, const float* bB1,
    float* ZB, _Float16* GoB, float* HfB){
    if (blockIdx.x < aCount)
        gemm_body<20,2,0>(nullptr, blockIdx.x, gaA, whA0, bA0, whA1, bA1,
                          ZA, GoA, HfA, nullptr, nullptr, nullptr, nullptr, 0);
    else
        gemm_body<11,2,0>(nullptr, blockIdx.x - aCount, gaB, whB0, bB0, whB1, bB1,
                          ZB, GoB, HfB, nullptr, nullptr, nullptr, nullptr, 0);
}

// F6: A = L1 h GEMM + proj (NK=20, EPI=2); B = L0 h GEMM (NK=11, EPI=1)
__global__ __launch_bounds__(256) void k_f6(int aCount,
    GA gaA, const _Float16* whA, const float* bA,
    float* ZA, float* HfA, _Float16* HhA,
    const float* Wo, const float* bo, float* out, int t,
    GA gaB, const _Float16* whB, const float* bB,
    float* ZB, float* HfB, _Float16* HhB){
    __shared__ float spr[128];
    if (blockIdx.x < aCount)
        gemm_body<20,1,2>(spr, blockIdx.x, gaA, whA, bA, nullptr, nullptr,
                          ZA, nullptr, HfA, HhA, Wo, bo, out, t);
    else
        gemm_body<11,1,1>(spr, blockIdx.x - aCount, gaB, whB, bB, nullptr, nullptr,
                          ZB, nullptr, HfB, HhB, nullptr, nullptr, nullptr, 0);
}

// ---------------- launcher ----------------

extern "C" void kernel_launch(void* const* d_in, const int* in_sizes, int n_in,
                              void* d_out, int out_size, void* d_ws, size_t ws_size,
                              hipStream_t stream){
    (void)in_sizes; (void)n_in; (void)out_size; (void)ws_size;
    const float* x  = (const float*)d_in[0];
    const int*   ei = (const int*)d_in[1];
    const float* Wz[2] = {(const float*)d_in[2],  (const float*)d_in[8]};
    const float* bz[2] = {(const float*)d_in[3],  (const float*)d_in[9]};
    const float* Wr[2] = {(const float*)d_in[4],  (const float*)d_in[10]};
    const float* br[2] = {(const float*)d_in[5],  (const float*)d_in[11]};
    const float* Wh[2] = {(const float*)d_in[6],  (const float*)d_in[12]};
    const float* bh[2] = {(const float*)d_in[7],  (const float*)d_in[13]};
    const float* Wo = (const float*)d_in[14];
    const float* bo = (const float*)d_in[15];
    float* out = (float*)d_out;

    char* p = (char*)d_ws;
    auto alloc = [&](size_t bytes)->char*{
        char* r = p; p += (bytes + 255) & ~(size_t)255; return r;
    };
    const size_t H64  = (size_t)NB*64*2;
    const size_t F64  = (size_t)NB*64*4;

    _Float16* Xtph = (_Float16*)alloc((size_t)SEQT*NB*2*2);
    float*    h0f = (float*)alloc(F64);
    float*    h1f = (float*)alloc(F64);
    float*    Z0  = (float*)alloc(F64);
    float*    Z1  = (float*)alloc(F64);
    _Float16* h0hb[2];
    h0hb[0] = (_Float16*)alloc(H64);
    h0hb[1] = (_Float16*)alloc(H64);
    _Float16* h1h = (_Float16*)alloc(H64);
    _Float16* XTh = (_Float16*)alloc((size_t)NB*32*2);
    _Float16* Th1o = (_Float16*)alloc(H64);
    _Float16* Th1i = (_Float16*)alloc(H64);
    _Float16* Th2o = (_Float16*)alloc(H64);
    _Float16* Th2i = (_Float16*)alloc(H64);
    _Float16* G0L0 = (_Float16*)alloc(H64);
    _Float16* G1o0 = (_Float16*)alloc(H64);
    _Float16* G1i0 = (_Float16*)alloc(H64);
    _Float16* G2o0 = (_Float16*)alloc(H64);
    _Float16* G2i0 = (_Float16*)alloc(H64);
    _Float16* T1o64 = (_Float16*)alloc(H64);
    _Float16* T1i64 = (_Float16*)alloc(H64);
    _Float16* U2o64 = (_Float16*)alloc(H64);
    _Float16* U2i64 = (_Float16*)alloc(H64);
    _Float16* G0p  = (_Float16*)alloc(H64);
    _Float16* G1o1 = (_Float16*)alloc(H64);
    _Float16* G1i1 = (_Float16*)alloc(H64);
    _Float16* G2o1 = (_Float16*)alloc(H64);
    _Float16* G2i1 = (_Float16*)alloc(H64);
    _Float16 *whl0[3], *whl1[3];
    for (int g=0; g<3; ++g){
        whl0[g] = (_Float16*)alloc((size_t)4*11*64*8*2);
        whl1[g] = (_Float16*)alloc((size_t)4*20*64*8*2);
    }
    int* deg_out = (int*)alloc(NNODES*4);
    int* deg_in  = (int*)alloc(NNODES*4);
    int* row_ptr = (int*)alloc((NNODES+1)*4);
    int* cursor  = (int*)alloc(NNODES*4);
    int* csr_src = (int*)alloc(NEDGES*4);
    float* csr_wo = (float*)alloc(NEDGES*4);
    float* csr_wi = (float*)alloc(NEDGES*4);

    hipMemsetAsync(deg_out, 0, NNODES*4, stream);
    hipMemsetAsync(deg_in,  0, NNODES*4, stream);
    hipMemsetAsync(cursor,  0, NNODES*4, stream);
    hipMemsetAsync(h0f, 0, F64, stream);
    hipMemsetAsync(h1f, 0, F64, stream);
    hipMemsetAsync(h0hb[0], 0, H64, stream);
    hipMemsetAsync(h0hb[1], 0, H64, stream);
    hipMemsetAsync(h1h, 0, H64, stream);
    hipMemsetAsync(XTh, 0, (size_t)NB*32*2, stream);

    count_deg_k<<<(NEDGES+255)/256, 256, 0, stream>>>(ei, deg_out, deg_in);
    scan_k<<<1, 256, 0, stream>>>(deg_in, row_ptr);
    fill_csr_k<<<(NEDGES+255)/256, 256, 0, stream>>>(ei, deg_out, deg_in, row_ptr,
                                                     cursor, csr_src, csr_wo, csr_wi);
    prepack_x_k<<<(SEQT*NB*2+255)/256, 256, 0, stream>>>(x, Xtph);
    const float* Wptr0[3] = {Wz[0], Wr[0], Wh[0]};
    const float* Wptr1[3] = {Wz[1], Wr[1], Wh[1]};
    for (int g=0; g<3; ++g){
        pack_l0_k<<<(4*11*64+255)/256, 256, 0, stream>>>(Wptr0[g], whl0[g]);
        pack_l1_k<<<(4*20*64+255)/256, 256, 0, stream>>>(Wptr1[g], whl1[g]);
    }

    // GEMM K-block descriptor tables (strides in halves); parity over h0 buffer.
    GA gaL0zr[2] = {}, gaL1zr[2] = {}, gaL1h[2] = {}, gaL0h = {};
    const _Float16* hsrc[4] = {Th1o, Th1i, Th2o, Th2i};
    const _Float16* g64s[4] = {T1o64, T1i64, U2o64, U2i64};
    for (int pp=0; pp<2; ++pp){
        const _Float16* t64[5] = {h0hb[pp], Th1o, Th1i, Th2o, Th2i};
        gaL0zr[pp].kd[0] = {XTh, 32};
        for (int s=0; s<5; ++s){
            gaL0zr[pp].kd[1+2*s] = {t64[s], 64};
            gaL0zr[pp].kd[2+2*s] = {t64[s]+32, 64};
        }
        gaL1zr[pp].kd[0] = {h0hb[pp], 64};    gaL1zr[pp].kd[1] = {h0hb[pp]+32, 64};
        gaL1zr[pp].kd[2] = {h1h, 64};         gaL1zr[pp].kd[3] = {h1h+32, 64};
        for (int s=0; s<4; ++s){
            gaL1zr[pp].kd[4+4*s+0] = {hsrc[s], 64};
            gaL1zr[pp].kd[4+4*s+1] = {hsrc[s]+32, 64};
            gaL1zr[pp].kd[4+4*s+2] = {g64s[s], 64};
            gaL1zr[pp].kd[4+4*s+3] = {g64s[s]+32, 64};
        }
        gaL1h[pp].kd[0] = {h0hb[pp], 64};  gaL1h[pp].kd[1] = {h0hb[pp]+32, 64};
        gaL1h[pp].kd[2] = {G0p, 64};       gaL1h[pp].kd[3] = {G0p+32, 64};
        const _Float16* gh[4] = {G1o1, G1i1, G2o1, G2i1};
        for (int s=0; s<4; ++s){
            gaL1h[pp].kd[4+4*s+0] = {hsrc[s], 64};
            gaL1h[pp].kd[4+4*s+1] = {hsrc[s]+32, 64};
            gaL1h[pp].kd[4+4*s+2] = {gh[s], 64};
            gaL1h[pp].kd[4+4*s+3] = {gh[s]+32, 64};
        }
    }
    {
        const _Float16* g64[5] = {G0L0, G1o0, G1i0, G2o0, G2i0};
        gaL0h.kd[0] = {XTh, 32};
        for (int s=0; s<5; ++s){
            gaL0h.kd[1+2*s] = {g64[s], 64};
            gaL0h.kd[2+2*s] = {g64[s]+32, 64};
        }
    }

    // ---- prologue: L0(0) only (B-halves, aCount=0); reads h0(-1)=0 at parity 1 ----
    k_f1<<<NNODES, 64, 0, stream>>>(0, h0hb[1], h1h, T1o64, T1i64,
        Xtph, Th1o, Th1i, XTh, row_ptr, csr_src, csr_wo, csr_wi);
    k_f2<<<2*NNODES, 64, 0, stream>>>(0, T1o64, T1i64, U2o64, U2i64,
        Th1o, Th1i, Th2o, Th2i, XTh, row_ptr, csr_src, csr_wo, csr_wi);
    k_f3<<<625, 256, 0, stream>>>(0,
        gaL1zr[1], whl1[0], bz[1], whl1[1], br[1], Z1, G0p, h1f,
        gaL0zr[1], whl0[0], bz[0], whl0[1], br[0], Z0, G0L0, h0f);
    k_f4<<<NNODES, 64, 0, stream>>>(0, G0p, G1o1, G1i1, G0L0, G1o0, G1i0,
        row_ptr, csr_src, csr_wo, csr_wi);
    k_f5<<<2*NNODES, 64, 0, stream>>>(0, G1o1, G1i1, G2o1, G2i1,
        G1o0, G1i0, G2o0, G2i0, row_ptr, csr_src, csr_wo, csr_wi);
    k_f6<<<625, 256, 0, stream>>>(0,
        gaL1h[1], whl1[2], bh[1], Z1, h1f, h1h, Wo, bo, out, 0,
        gaL0h, whl0[2], bh[0], Z0, h0f, h0hb[0]);

    // ---- main pipelined loop: iteration s = L1(s) [A] + L0(s+1) [B] ----
    for (int s=0; s<SEQT; ++s){
        const int pr = s & 1;
        const int doB = (s+1 < SEQT) ? 1 : 0;
        const _Float16* xp = Xtph + (size_t)(doB ? s+1 : s)*NB*2;
        k_f1<<<2*NNODES, 64, 0, stream>>>(NNODES,
            h0hb[pr], h1h, T1o64, T1i64, xp, Th1o, Th1i, XTh,
            row_ptr, csr_src, csr_wo, csr_wi);
        k_f2<<<4*NNODES, 64, 0, stream>>>(2*NNODES,
            T1o64, T1i64, U2o64, U2i64,
            Th1o, Th1i, Th2o, Th2i, XTh, row_ptr, csr_src, csr_wo, csr_wi);
        k_f3<<<625*(1+doB), 256, 0, stream>>>(625,
            gaL1zr[pr], whl1[0], bz[1], whl1[1], br[1], Z1, G0p, h1f,
            gaL0zr[pr], whl0[0], bz[0], whl0[1], br[0], Z0, G0L0, h0f);
        k_f4<<<NNODES*(1+doB), 64, 0, stream>>>(NNODES,
            G0p, G1o1, G1i1, G0L0, G1o0, G1i0, row_ptr, csr_src, csr_wo, csr_wi);
        k_f5<<<2*NNODES*(1+doB), 64, 0, stream>>>(2*NNODES,
            G1o1, G1i1, G2o1, G2i1, G1o0, G1i0, G2o0, G2i0,
            row_ptr, csr_src, csr_wo, csr_wi);
        k_f6<<<625*(1+doB), 256, 0, stream>>>(625,
            gaL1h[pr], whl1[2], bh[1], Z1, h1f, h1h, Wo, bo, out, s,
            gaL0h, whl0[2], bh[0], Z0, h0f, h0hb[(s+1)&1]);
    }
}

// Round 13
// 1929.190 us; speedup vs baseline: 1.0420x; 1.0420x over previous
//
#include <hip/hip_runtime.h>
#include <math.h>

#define NNODES 5000
#define NEDGES 50000
#define SEQT 12
#define NB 40000
#define MAXDEG 128

typedef __attribute__((ext_vector_type(8))) _Float16 half8;
typedef __attribute__((ext_vector_type(2))) _Float16 half2v;
typedef __attribute__((ext_vector_type(4))) float f32x4;

// ---------------- setup kernels ----------------

__global__ void count_deg_k(const int* __restrict__ ei, int* deg_out, int* deg_in){
    int e = blockIdx.x*blockDim.x + threadIdx.x;
    if (e < NEDGES){
        atomicAdd(&deg_out[ei[e]], 1);
        atomicAdd(&deg_in[ei[NEDGES + e]], 1);
    }
}

__global__ void scan_k(const int* __restrict__ deg_in, int* __restrict__ row_ptr){
    __shared__ int part[256];
    int tid = threadIdx.x;
    int base = tid*20;
    int loc[20]; int s = 0;
    for (int i=0;i<20;i++){
        int idx = base+i;
        int v = (idx < NNODES) ? deg_in[idx] : 0;
        loc[i] = s; s += v;
    }
    part[tid] = s;
    __syncthreads();
    for (int off=1; off<256; off<<=1){
        int v = (tid>=off) ? part[tid-off] : 0;
        __syncthreads();
        part[tid] += v;
        __syncthreads();
    }
    int prev = (tid==0) ? 0 : part[tid-1];
    for (int i=0;i<20;i++){
        int idx = base+i;
        if (idx < NNODES) row_ptr[idx] = prev + loc[i];
    }
    if (tid==255) row_ptr[NNODES] = part[255];
}

__global__ void fill_csr_k(const int* __restrict__ ei, const int* __restrict__ deg_out,
                           const int* __restrict__ deg_in, const int* __restrict__ row_ptr,
                           int* cursor, int* __restrict__ csr_src,
                           float* __restrict__ csr_wo, float* __restrict__ csr_wi){
    int e = blockIdx.x*blockDim.x + threadIdx.x;
    if (e >= NEDGES) return;
    int s = ei[e], d = ei[NEDGES+e];
    int pos = atomicAdd(&cursor[d], 1);
    int slot = row_ptr[d] + pos;
    csr_src[slot] = s;
    csr_wo[slot] = 1.f/(float)deg_out[s];
    csr_wi[slot] = 1.f/(float)deg_in[d];
}

// pre-pack x for all timesteps: Xtph[t][row][2] fp16, row = n*8+b
__global__ void prepack_x_k(const float* __restrict__ x, _Float16* __restrict__ Xtph){
    int idx = blockIdx.x*256 + threadIdx.x;
    if (idx >= SEQT*NB*2) return;
    int tt = idx / (NB*2);
    int r2 = idx - tt*(NB*2);
    int row = r2 >> 1, f = r2 & 1;
    int n = row >> 3, b = row & 7;
    Xtph[idx] = (_Float16)x[((size_t)(b*SEQT+tt)*NNODES + n)*2 + f];
}

// ---------------- weight packing (refolded basis, fp16, ks-major MFMA B-frag) ----------------
__device__ __forceinline__ float wfetch(const float* __restrict__ W, int F, int slot, int f, int c){
    const float* p0 = W + ((size_t)0*F + f)*64 + c;
    const float* p1 = W + ((size_t)1*F + f)*64 + c;
    const float* p2 = W + ((size_t)2*F + f)*64 + c;
    const float* p3 = W + ((size_t)3*F + f)*64 + c;
    const float* p4 = W + ((size_t)4*F + f)*64 + c;
    const float* p5 = W + ((size_t)5*F + f)*64 + c;
    switch(slot){
        case 0: return *p0 + *p3 - *p2 - *p5;
        case 1: return *p1;
        case 2: return *p4;
        case 3: return 2.f * *p2;
        default: return 2.f * *p5;
    }
}

__global__ void pack_l0_k(const float* __restrict__ W, _Float16* __restrict__ wh){
    int idx = blockIdx.x*256 + threadIdx.x;
    if (idx >= 4*11*64) return;
    int lane = idx & 63, rest = idx >> 6;
    int ks = rest % 11, cf = rest / 11;
    int col = cf*16 + (lane & 15);
    int kb = ks*32 + ((lane>>4)<<3);
    size_t o = ((size_t)(ks*4 + cf)*64 + lane)*8;
    for (int j=0;j<8;j++){
        int k = kb + j;
        float v = 0.f;
        if (ks == 0){
            if (k < 10) v = wfetch(W, 66, k>>1, k&1, col);
        } else {
            int slot = (ks-1)>>1;
            int f = 2 + k - 32 - 64*slot;
            v = wfetch(W, 66, slot, f, col);
        }
        wh[o+j] = (_Float16)v;
    }
}

__global__ void pack_l1_k(const float* __restrict__ W, _Float16* __restrict__ wh){
    int idx = blockIdx.x*256 + threadIdx.x;
    if (idx >= 4*20*64) return;
    int lane = idx & 63, rest = idx >> 6;
    int ks = rest % 20, cf = rest / 20;
    int col = cf*16 + (lane & 15);
    int kb = ks*32 + ((lane>>4)<<3);
    int slot = ks >> 2;
    size_t o = ((size_t)(ks*4 + cf)*64 + lane)*8;
    for (int j=0;j<8;j++){
        int k = kb + j;
        int f = k - slot*128;
        wh[o+j] = (_Float16)wfetch(W, 128, slot, f, col);
    }
}

// ---------------- fused pipelined stage kernels ----------------
// Iteration s fuses: A = L1 stage of timestep s, B = L0 stage of timestep s+1.
// h0-derived props (Th1*, Th2*) are shared between L0(s+1) and L1(s) — computed once (B-half).

// F1: A = dual prop of h1h -> T1o64/T1i64; B = dual prop of h0h -> Th1o/Th1i + x side-channel
__global__ __launch_bounds__(64) void k_f1(int aCount,
    const _Float16* __restrict__ h0h, const _Float16* __restrict__ h1h,
    _Float16* __restrict__ T1o64, _Float16* __restrict__ T1i64,
    const _Float16* __restrict__ Xt,
    _Float16* __restrict__ Th1o, _Float16* __restrict__ Th1i, _Float16* __restrict__ XTh,
    const int* __restrict__ rp, const int* __restrict__ cs,
    const float* __restrict__ cwo, const float* __restrict__ cwi){
    __shared__ int s_o[MAXDEG]; __shared__ float swo[MAXDEG], swi[MAXDEG];
    const int bx = blockIdx.x;
    const bool isA = bx < aCount;
    const int n = isA ? bx : bx - aCount;
    int beg = rp[n], deg = rp[n+1]-beg;
    int nst = deg < MAXDEG ? deg : MAXDEG;
    for (int j=threadIdx.x; j<nst; j+=64){
        s_o[j] = cs[beg+j]*512;
        swo[j] = cwo[beg+j]; swi[j] = cwi[beg+j];
    }
    __syncthreads();
    const _Float16* S = isA ? h1h : h0h;
    _Float16* Yo = isA ? T1o64 : Th1o;
    _Float16* Yi = isA ? T1i64 : Th1i;
    int off = threadIdx.x*8;
    {
        float ao[8] = {0,0,0,0,0,0,0,0}, ai[8] = {0,0,0,0,0,0,0,0};
        for (int j=0;j<nst;j++){
            half8 v = *(const half8*)(S + s_o[j] + off);
            float wo=swo[j], wi=swi[j];
            #pragma unroll
            for (int e=0;e<8;e++){
                float xv = (float)v[e];
                ao[e]=fmaf(wo,xv,ao[e]); ai[e]=fmaf(wi,xv,ai[e]);
            }
        }
        for (int j=nst;j<deg;j++){
            half8 v = *(const half8*)(S + (size_t)cs[beg+j]*512 + off);
            float wo=cwo[beg+j], wi=cwi[beg+j];
            #pragma unroll
            for (int e=0;e<8;e++){
                float xv = (float)v[e];
                ao[e]=fmaf(wo,xv,ao[e]); ai[e]=fmaf(wi,xv,ai[e]);
            }
        }
        half8 po, pi;
        #pragma unroll
        for (int e=0;e<8;e++){ po[e]=(_Float16)ao[e]; pi[e]=(_Float16)ai[e]; }
        *(half8*)(Yo + (size_t)n*512 + off) = po;
        *(half8*)(Yi + (size_t)n*512 + off) = pi;
    }
    if (!isA && threadIdx.x < 8){
        int b = threadIdx.x;
        float ax0=0,ax1=0, ay0=0,ay1=0;
        for (int j=0;j<nst;j++){
            int src = s_o[j] >> 9;
            half2v v = *(const half2v*)(Xt + src*16 + b*2);
            float x0=(float)v[0], x1=(float)v[1];
            ax0=fmaf(swo[j],x0,ax0); ax1=fmaf(swo[j],x1,ax1);
            ay0=fmaf(swi[j],x0,ay0); ay1=fmaf(swi[j],x1,ay1);
        }
        for (int j=nst;j<deg;j++){
            int src = cs[beg+j];
            half2v v = *(const half2v*)(Xt + src*16 + b*2);
            float x0=(float)v[0], x1=(float)v[1];
            ax0=fmaf(cwo[beg+j],x0,ax0); ax1=fmaf(cwo[beg+j],x1,ax1);
            ay0=fmaf(cwi[beg+j],x0,ay0); ay1=fmaf(cwi[beg+j],x1,ay1);
        }
        size_t ro = (size_t)(n*8 + b)*32;
        XTh[ro+0] = Xt[(size_t)(n*8+b)*2+0];
        XTh[ro+1] = Xt[(size_t)(n*8+b)*2+1];
        XTh[ro+2] = (_Float16)ax0; XTh[ro+3] = (_Float16)ax1;
        XTh[ro+4] = (_Float16)ay0; XTh[ro+5] = (_Float16)ay1;
    }
}

// F2: A = single-dir prop T1{o,i}64 -> U2{o,i}64 (2N blocks); B = Th1* -> Th2* + x side-channel (2N blocks)
__global__ __launch_bounds__(64) void k_f2(int aCount,
    const _Float16* __restrict__ T1o64, const _Float16* __restrict__ T1i64,
    _Float16* __restrict__ U2o64, _Float16* __restrict__ U2i64,
    const _Float16* __restrict__ Th1o, const _Float16* __restrict__ Th1i,
    _Float16* __restrict__ Th2o, _Float16* __restrict__ Th2i, _Float16* __restrict__ XTh,
    const int* __restrict__ rp, const int* __restrict__ cs,
    const float* __restrict__ cwo, const float* __restrict__ cwi){
    __shared__ int s_o[MAXDEG]; __shared__ float s_w[MAXDEG];
    const int bx = blockIdx.x;
    const bool isA = bx < aCount;
    const int idx = isA ? bx : bx - aCount;
    const int n = idx >> 1, sel = idx & 1;
    const float* cw = sel ? cwi : cwo;
    int beg = rp[n], deg = rp[n+1]-beg;
    int nst = deg < MAXDEG ? deg : MAXDEG;
    for (int j=threadIdx.x; j<nst; j+=64){
        s_o[j] = cs[beg+j]*512;
        s_w[j] = cw[beg+j];
    }
    __syncthreads();
    const _Float16* S = isA ? (sel ? T1i64 : T1o64) : (sel ? Th1i : Th1o);
    _Float16* U = isA ? (sel ? U2i64 : U2o64) : (sel ? Th2i : Th2o);
    int off = threadIdx.x*8;
    {
        float a[8] = {0,0,0,0,0,0,0,0};
        for (int j=0;j<nst;j++){
            half8 v = *(const half8*)(S + s_o[j] + off);
            float w=s_w[j];
            #pragma unroll
            for (int e=0;e<8;e++) a[e]=fmaf(w,(float)v[e],a[e]);
        }
        for (int j=nst;j<deg;j++){
            half8 v = *(const half8*)(S + (size_t)cs[beg+j]*512 + off);
            float w=cw[beg+j];
            #pragma unroll
            for (int e=0;e<8;e++) a[e]=fmaf(w,(float)v[e],a[e]);
        }
        half8 p;
        #pragma unroll
        for (int e=0;e<8;e++) p[e]=(_Float16)a[e];
        *(half8*)(U + (size_t)n*512 + off) = p;
    }
    if (!isA && threadIdx.x < 8){
        int b = threadIdx.x;
        int xo = 2 + 2*sel;
        float a0=0,a1=0;
        for (int j=0;j<nst;j++){
            int src = s_o[j] >> 9;
            half2v v = *(const half2v*)(XTh + (size_t)src*256 + b*32 + xo);
            a0=fmaf(s_w[j],(float)v[0],a0); a1=fmaf(s_w[j],(float)v[1],a1);
        }
        for (int j=nst;j<deg;j++){
            int src = cs[beg+j];
            float w = cw[beg+j];
            half2v v = *(const half2v*)(XTh + (size_t)src*256 + b*32 + xo);
            a0=fmaf(w,(float)v[0],a0); a1=fmaf(w,(float)v[1],a1);
        }
        size_t ro = (size_t)(n*8 + b)*32 + 6 + 2*sel;
        XTh[ro+0] = (_Float16)a0; XTh[ro+1] = (_Float16)a1;
    }
}

// F4: dual prop of 64-wide G tensors (A and B halves, identical body, ptr select)
__global__ __launch_bounds__(64) void k_f4(int aCount,
    const _Float16* __restrict__ SA, _Float16* __restrict__ YoA, _Float16* __restrict__ YiA,
    const _Float16* __restrict__ SB, _Float16* __restrict__ YoB, _Float16* __restrict__ YiB,
    const int* __restrict__ rp, const int* __restrict__ cs,
    const float* __restrict__ cwo, const float* __restrict__ cwi){
    __shared__ int s_o[MAXDEG]; __shared__ float swo[MAXDEG], swi[MAXDEG];
    const int bx = blockIdx.x;
    const bool isA = bx < aCount;
    const int n = isA ? bx : bx - aCount;
    const _Float16* S = isA ? SA : SB;
    _Float16* Yo = isA ? YoA : YoB;
    _Float16* Yi = isA ? YiA : YiB;
    int beg = rp[n], deg = rp[n+1]-beg;
    int nst = deg < MAXDEG ? deg : MAXDEG;
    for (int j=threadIdx.x; j<nst; j+=64){
        s_o[j] = cs[beg+j]*512;
        swo[j] = cwo[beg+j]; swi[j] = cwi[beg+j];
    }
    __syncthreads();
    int off = threadIdx.x*8;
    float ao[8] = {0,0,0,0,0,0,0,0}, ai[8] = {0,0,0,0,0,0,0,0};
    for (int j=0;j<nst;j++){
        half8 v = *(const half8*)(S + s_o[j] + off);
        float wo=swo[j], wi=swi[j];
        #pragma unroll
        for (int e=0;e<8;e++){
            float xv = (float)v[e];
            ao[e]=fmaf(wo,xv,ao[e]); ai[e]=fmaf(wi,xv,ai[e]);
        }
    }
    for (int j=nst;j<deg;j++){
        half8 v = *(const half8*)(S + (size_t)cs[beg+j]*512 + off);
        float wo=cwo[beg+j], wi=cwi[beg+j];
        #pragma unroll
        for (int e=0;e<8;e++){
            float xv = (float)v[e];
            ao[e]=fmaf(wo,xv,ao[e]); ai[e]=fmaf(wi,xv,ai[e]);
        }
    }
    half8 po, pi;
    #pragma unroll
    for (int e=0;e<8;e++){ po[e]=(_Float16)ao[e]; pi[e]=(_Float16)ai[e]; }
    *(half8*)(Yo + (size_t)n*512 + off) = po;
    *(half8*)(Yi + (size_t)n*512 + off) = pi;
}

// F5: second hop of 64-wide G tensors (A and B halves, sel = idx&1)
__global__ __launch_bounds__(64) void k_f5(int aCount,
    const _Float16* __restrict__ T1oA, const _Float16* __restrict__ T1iA,
    _Float16* __restrict__ U2oA, _Float16* __restrict__ U2iA,
    const _Float16* __restrict__ T1oB, const _Float16* __restrict__ T1iB,
    _Float16* __restrict__ U2oB, _Float16* __restrict__ U2iB,
    const int* __restrict__ rp, const int* __restrict__ cs,
    const float* __restrict__ cwo, const float* __restrict__ cwi){
    __shared__ int s_o[MAXDEG]; __shared__ float s_w[MAXDEG];
    const int bx = blockIdx.x;
    const bool isA = bx < aCount;
    const int idx = isA ? bx : bx - aCount;
    const int n = idx >> 1, sel = idx & 1;
    const _Float16* S = isA ? (sel ? T1iA : T1oA) : (sel ? T1iB : T1oB);
    _Float16* U = isA ? (sel ? U2iA : U2oA) : (sel ? U2iB : U2oB);
    const float* cw = sel ? cwi : cwo;
    int beg = rp[n], deg = rp[n+1]-beg;
    int nst = deg < MAXDEG ? deg : MAXDEG;
    for (int j=threadIdx.x; j<nst; j+=64){
        s_o[j] = cs[beg+j]*512;
        s_w[j] = cw[beg+j];
    }
    __syncthreads();
    int off = threadIdx.x*8;
    float a[8] = {0,0,0,0,0,0,0,0};
    for (int j=0;j<nst;j++){
        half8 v = *(const half8*)(S + s_o[j] + off);
        float w=s_w[j];
        #pragma unroll
        for (int e=0;e<8;e++) a[e]=fmaf(w,(float)v[e],a[e]);
    }
    for (int j=nst;j<deg;j++){
        half8 v = *(const half8*)(S + (size_t)cs[beg+j]*512 + off);
        float w=cw[beg+j];
        #pragma unroll
        for (int e=0;e<8;e++) a[e]=fmaf(w,(float)v[e],a[e]);
    }
    half8 p;
    #pragma unroll
    for (int e=0;e<8;e++) p[e]=(_Float16)a[e];
    *(half8*)(U + (size_t)n*512 + off) = p;
}

// ---------------- MFMA f16 GEMM body (LDS-staged B, double-buffered, 32x32 wave tiles) ----------------

struct KD { const _Float16* a; int st; };
struct GA { KD kd[20]; };

template<int NK, int NG, int EPI>
__device__ __forceinline__ void gemm_body(char* smemraw, int bxm, const GA& ga,
    const _Float16* __restrict__ wh0, const float* __restrict__ b0,
    const _Float16* __restrict__ wh1, const float* __restrict__ b1,
    _Float16* __restrict__ Z, _Float16* __restrict__ Gout,
    float* __restrict__ Hf, _Float16* __restrict__ Hh,
    const float* __restrict__ Wo, const float* __restrict__ bo,
    float* __restrict__ out, int t){
    _Float16* ldsb = (_Float16*)smemraw;                         // [2][NG*2048]
    float* spr = (float*)(smemraw + (size_t)4*NG*2048);          // [4][32]
    const int tid = threadIdx.x;
    const int lane = tid & 63, wv = tid >> 6, rl = lane & 15, kg = lane >> 4;
    const int m0 = bxm*64 + (wv&1)*32;
    const int cfb = (wv>>1)*2;
    const _Float16* wsrc[2] = {wh0, wh1};

    half8 srg[NG];
    half8 a0, a1, a0n, a1n;

    auto sload = [&](int ks){
        #pragma unroll
        for (int j=0;j<NG;j++)
            srg[j] = *(const half8*)(wsrc[j] + (size_t)ks*2048 + tid*8);
    };
    auto swrite = [&](int buf){
        #pragma unroll
        for (int j=0;j<NG;j++)
            *(half8*)&ldsb[buf*(NG*2048) + j*2048 + tid*8] = srg[j];
    };
    auto aload = [&](int ks, half8& x0, half8& x1){
        const _Float16* base = ga.kd[ks].a;
        const int st = ga.kd[ks].st;
        x0 = *(const half8*)(base + (size_t)(m0+rl)*st + kg*8);
        x1 = *(const half8*)(base + (size_t)(m0+16+rl)*st + kg*8);
    };

    f32x4 acc[NG][2][2];
    #pragma unroll
    for (int g=0; g<NG; ++g)
        #pragma unroll
        for (int cc=0; cc<2; ++cc)
            #pragma unroll
            for (int mr=0; mr<2; ++mr){
                acc[g][cc][mr][0]=0.f; acc[g][cc][mr][1]=0.f;
                acc[g][cc][mr][2]=0.f; acc[g][cc][mr][3]=0.f;
            }

    sload(0); swrite(0);
    if (NK>1) sload(1);
    aload(0, a0, a1);
    __syncthreads();
    for (int ks=0; ks<NK; ++ks){
        const int cur = ks & 1;
        if (ks+1 < NK){ swrite(cur^1); aload(ks+1, a0n, a1n); }
        if (ks+2 < NK) sload(ks+2);
        #pragma unroll
        for (int g=0; g<NG; ++g){
            #pragma unroll
            for (int cc=0; cc<2; ++cc){
                half8 bv = *(const half8*)&ldsb[cur*(NG*2048) + g*2048 + (cfb+cc)*512 + lane*8];
                acc[g][cc][0] = __builtin_amdgcn_mfma_f32_16x16x32_f16(a0, bv, acc[g][cc][0], 0, 0, 0);
                acc[g][cc][1] = __builtin_amdgcn_mfma_f32_16x16x32_f16(a1, bv, acc[g][cc][1], 0, 0, 0);
            }
        }
        __syncthreads();
        a0 = a0n; a1 = a1n;
    }

    if constexpr (EPI == 0){
        #pragma unroll
        for (int cc=0; cc<2; ++cc){
            const int col = (cfb+cc)*16 + rl;
            float bzv = b0[col], brv = b1[col];
            #pragma unroll
            for (int mr=0; mr<2; ++mr)
                #pragma unroll
                for (int i=0;i<4;i++){
                    int row = m0 + mr*16 + kg*4 + i;
                    float z = 1.f/(1.f+__expf(-(acc[0][cc][mr][i] + bzv)));
                    float r = 1.f/(1.f+__expf(-(acc[NG-1][cc][mr][i] + brv)));
                    size_t ix = (size_t)row*64 + col;
                    Z[ix] = (_Float16)z;
                    Gout[ix] = (_Float16)(Hf[ix]*r);
                }
        }
    } else {
        float pr[2][4] = {{0.f,0.f,0.f,0.f},{0.f,0.f,0.f,0.f}};
        #pragma unroll
        for (int cc=0; cc<2; ++cc){
            const int col = (cfb+cc)*16 + rl;
            float bv = b0[col];
            float wo_c = 0.f;
            if constexpr (EPI == 2) wo_c = Wo[col];
            #pragma unroll
            for (int mr=0; mr<2; ++mr)
                #pragma unroll
                for (int i=0;i<4;i++){
                    int row = m0 + mr*16 + kg*4 + i;
                    float ht = tanhf(acc[0][cc][mr][i] + bv);
                    size_t ix = (size_t)row*64 + col;
                    float z = (float)Z[ix];
                    float hn = z*Hf[ix] + (1.f-z)*ht;
                    Hf[ix] = hn;
                    Hh[ix] = (_Float16)hn;
                    if constexpr (EPI == 2) pr[mr][i] = fmaf(hn, wo_c, pr[mr][i]);
                }
        }
        if constexpr (EPI == 2){
            #pragma unroll
            for (int mr=0; mr<2; ++mr)
                #pragma unroll
                for (int i=0;i<4;i++){
                    float v = pr[mr][i];
                    v += __shfl_xor(v, 1);
                    v += __shfl_xor(v, 2);
                    v += __shfl_xor(v, 4);
                    v += __shfl_xor(v, 8);
                    if (rl == 0) spr[wv*32 + mr*16 + kg*4 + i] = v;
                }
            __syncthreads();
            if (tid < 64){
                int r = tid;
                float v = spr[(r>>5)*32 + (r&31)] + spr[((r>>5)|2)*32 + (r&31)] + bo[0];
                int row = bxm*64 + r;
                int n = row >> 3, b = row & 7;
                out[(size_t)(b*SEQT + t)*NNODES + n] = v;
            }
        }
    }
}

// F3: A = L1 z/r GEMM (NK=20); B = L0 z/r GEMM (NK=11)
__global__ __launch_bounds__(256) void k_f3(int aCount,
    GA gaA, const _Float16* whA0, const float* bA0, const _Float16* whA1, const float* bA1,
    _Float16* ZA, _Float16* GoA, float* HfA,
    GA gaB, const _Float16* whB0, const float* bB0, const _Float16* whB1, const float* bB1,
    _Float16* ZB, _Float16* GoB, float* HfB){
    __shared__ __align__(16) char smem[4*2*2048 + 512];
    if (blockIdx.x < aCount)
        gemm_body<20,2,0>(smem, blockIdx.x, gaA, whA0, bA0, whA1, bA1,
                          ZA, GoA, HfA, nullptr, nullptr, nullptr, nullptr, 0);
    else
        gemm_body<11,2,0>(smem, blockIdx.x - aCount, gaB, whB0, bB0, whB1, bB1,
                          ZB, GoB, HfB, nullptr, nullptr, nullptr, nullptr, 0);
}

// F6: A = L1 h GEMM + proj (NK=20, EPI=2); B = L0 h GEMM (NK=11, EPI=1)
__global__ __launch_bounds__(256) void k_f6(int aCount,
    GA gaA, const _Float16* whA, const float* bA,
    _Float16* ZA, float* HfA, _Float16* HhA,
    const float* Wo, const float* bo, float* out, int t,
    GA gaB, const _Float16* whB, const float* bB,
    _Float16* ZB, float* HfB, _Float16* HhB){
    __shared__ __align__(16) char smem[4*1*2048 + 512];
    if (blockIdx.x < aCount)
        gemm_body<20,1,2>(smem, blockIdx.x, gaA, whA, bA, nullptr, nullptr,
                          ZA, nullptr, HfA, HhA, Wo, bo, out, t);
    else
        gemm_body<11,1,1>(smem, blockIdx.x - aCount, gaB, whB, bB, nullptr, nullptr,
                          ZB, nullptr, HfB, HhB, nullptr, nullptr, nullptr, 0);
}

// ---------------- launcher ----------------

extern "C" void kernel_launch(void* const* d_in, const int* in_sizes, int n_in,
                              void* d_out, int out_size, void* d_ws, size_t ws_size,
                              hipStream_t stream){
    (void)in_sizes; (void)n_in; (void)out_size; (void)ws_size;
    const float* x  = (const float*)d_in[0];
    const int*   ei = (const int*)d_in[1];
    const float* Wz[2] = {(const float*)d_in[2],  (const float*)d_in[8]};
    const float* bz[2] = {(const float*)d_in[3],  (const float*)d_in[9]};
    const float* Wr[2] = {(const float*)d_in[4],  (const float*)d_in[10]};
    const float* br[2] = {(const float*)d_in[5],  (const float*)d_in[11]};
    const float* Wh[2] = {(const float*)d_in[6],  (const float*)d_in[12]};
    const float* bh[2] = {(const float*)d_in[7],  (const float*)d_in[13]};
    const float* Wo = (const float*)d_in[14];
    const float* bo = (const float*)d_in[15];
    float* out = (float*)d_out;

    char* p = (char*)d_ws;
    auto alloc = [&](size_t bytes)->char*{
        char* r = p; p += (bytes + 255) & ~(size_t)255; return r;
    };
    const size_t H64  = (size_t)NB*64*2;
    const size_t F64  = (size_t)NB*64*4;

    _Float16* Xtph = (_Float16*)alloc((size_t)SEQT*NB*2*2);
    float*    h0f = (float*)alloc(F64);
    float*    h1f = (float*)alloc(F64);
    _Float16* Z0  = (_Float16*)alloc(H64);
    _Float16* Z1  = (_Float16*)alloc(H64);
    _Float16* h0hb[2];
    h0hb[0] = (_Float16*)alloc(H64);
    h0hb[1] = (_Float16*)alloc(H64);
    _Float16* h1h = (_Float16*)alloc(H64);
    _Float16* XTh = (_Float16*)alloc((size_t)NB*32*2);
    _Float16* Th1o = (_Float16*)alloc(H64);
    _Float16* Th1i = (_Float16*)alloc(H64);
    _Float16* Th2o = (_Float16*)alloc(H64);
    _Float16* Th2i = (_Float16*)alloc(H64);
    _Float16* G0L0 = (_Float16*)alloc(H64);
    _Float16* G1o0 = (_Float16*)alloc(H64);
    _Float16* G1i0 = (_Float16*)alloc(H64);
    _Float16* G2o0 = (_Float16*)alloc(H64);
    _Float16* G2i0 = (_Float16*)alloc(H64);
    _Float16* T1o64 = (_Float16*)alloc(H64);
    _Float16* T1i64 = (_Float16*)alloc(H64);
    _Float16* U2o64 = (_Float16*)alloc(H64);
    _Float16* U2i64 = (_Float16*)alloc(H64);
    _Float16* G0p  = (_Float16*)alloc(H64);
    _Float16* G1o1 = (_Float16*)alloc(H64);
    _Float16* G1i1 = (_Float16*)alloc(H64);
    _Float16* G2o1 = (_Float16*)alloc(H64);
    _Float16* G2i1 = (_Float16*)alloc(H64);
    _Float16 *whl0[3], *whl1[3];
    for (int g=0; g<3; ++g){
        whl0[g] = (_Float16*)alloc((size_t)4*11*64*8*2);
        whl1[g] = (_Float16*)alloc((size_t)4*20*64*8*2);
    }
    int* deg_out = (int*)alloc(NNODES*4);
    int* deg_in  = (int*)alloc(NNODES*4);
    int* row_ptr = (int*)alloc((NNODES+1)*4);
    int* cursor  = (int*)alloc(NNODES*4);
    int* csr_src = (int*)alloc(NEDGES*4);
    float* csr_wo = (float*)alloc(NEDGES*4);
    float* csr_wi = (float*)alloc(NEDGES*4);

    hipMemsetAsync(deg_out, 0, NNODES*4, stream);
    hipMemsetAsync(deg_in,  0, NNODES*4, stream);
    hipMemsetAsync(cursor,  0, NNODES*4, stream);
    hipMemsetAsync(h0f, 0, F64, stream);
    hipMemsetAsync(h1f, 0, F64, stream);
    hipMemsetAsync(h0hb[0], 0, H64, stream);
    hipMemsetAsync(h0hb[1], 0, H64, stream);
    hipMemsetAsync(h1h, 0, H64, stream);
    hipMemsetAsync(XTh, 0, (size_t)NB*32*2, stream);

    count_deg_k<<<(NEDGES+255)/256, 256, 0, stream>>>(ei, deg_out, deg_in);
    scan_k<<<1, 256, 0, stream>>>(deg_in, row_ptr);
    fill_csr_k<<<(NEDGES+255)/256, 256, 0, stream>>>(ei, deg_out, deg_in, row_ptr,
                                                     cursor, csr_src, csr_wo, csr_wi);
    prepack_x_k<<<(SEQT*NB*2+255)/256, 256, 0, stream>>>(x, Xtph);
    const float* Wptr0[3] = {Wz[0], Wr[0], Wh[0]};
    const float* Wptr1[3] = {Wz[1], Wr[1], Wh[1]};
    for (int g=0; g<3; ++g){
        pack_l0_k<<<(4*11*64+255)/256, 256, 0, stream>>>(Wptr0[g], whl0[g]);
        pack_l1_k<<<(4*20*64+255)/256, 256, 0, stream>>>(Wptr1[g], whl1[g]);
    }

    // GEMM K-block descriptor tables (strides in halves); parity over h0 buffer.
    GA gaL0zr[2] = {}, gaL1zr[2] = {}, gaL1h[2] = {}, gaL0h = {};
    const _Float16* hsrc[4] = {Th1o, Th1i, Th2o, Th2i};
    const _Float16* g64s[4] = {T1o64, T1i64, U2o64, U2i64};
    for (int pp=0; pp<2; ++pp){
        const _Float16* t64[5] = {h0hb[pp], Th1o, Th1i, Th2o, Th2i};
        gaL0zr[pp].kd[0] = {XTh, 32};
        for (int s=0; s<5; ++s){
            gaL0zr[pp].kd[1+2*s] = {t64[s], 64};
            gaL0zr[pp].kd[2+2*s] = {t64[s]+32, 64};
        }
        gaL1zr[pp].kd[0] = {h0hb[pp], 64};    gaL1zr[pp].kd[1] = {h0hb[pp]+32, 64};
        gaL1zr[pp].kd[2] = {h1h, 64};         gaL1zr[pp].kd[3] = {h1h+32, 64};
        for (int s=0; s<4; ++s){
            gaL1zr[pp].kd[4+4*s+0] = {hsrc[s], 64};
            gaL1zr[pp].kd[4+4*s+1] = {hsrc[s]+32, 64};
            gaL1zr[pp].kd[4+4*s+2] = {g64s[s], 64};
            gaL1zr[pp].kd[4+4*s+3] = {g64s[s]+32, 64};
        }
        gaL1h[pp].kd[0] = {h0hb[pp], 64};  gaL1h[pp].kd[1] = {h0hb[pp]+32, 64};
        gaL1h[pp].kd[2] = {G0p, 64};       gaL1h[pp].kd[3] = {G0p+32, 64};
        const _Float16* gh[4] = {G1o1, G1i1, G2o1, G2i1};
        for (int s=0; s<4; ++s){
            gaL1h[pp].kd[4+4*s+0] = {hsrc[s], 64};
            gaL1h[pp].kd[4+4*s+1] = {hsrc[s]+32, 64};
            gaL1h[pp].kd[4+4*s+2] = {gh[s], 64};
            gaL1h[pp].kd[4+4*s+3] = {gh[s]+32, 64};
        }
    }
    {
        const _Float16* g64[5] = {G0L0, G1o0, G1i0, G2o0, G2i0};
        gaL0h.kd[0] = {XTh, 32};
        for (int s=0; s<5; ++s){
            gaL0h.kd[1+2*s] = {g64[s], 64};
            gaL0h.kd[2+2*s] = {g64[s]+32, 64};
        }
    }

    // ---- prologue: L0(0) only (B-halves, aCount=0); reads h0(-1)=0 at parity 1 ----
    k_f1<<<NNODES, 64, 0, stream>>>(0, h0hb[1], h1h, T1o64, T1i64,
        Xtph, Th1o, Th1i, XTh, row_ptr, csr_src, csr_wo, csr_wi);
    k_f2<<<2*NNODES, 64, 0, stream>>>(0, T1o64, T1i64, U2o64, U2i64,
        Th1o, Th1i, Th2o, Th2i, XTh, row_ptr, csr_src, csr_wo, csr_wi);
    k_f3<<<625, 256, 0, stream>>>(0,
        gaL1zr[1], whl1[0], bz[1], whl1[1], br[1], Z1, G0p, h1f,
        gaL0zr[1], whl0[0], bz[0], whl0[1], br[0], Z0, G0L0, h0f);
    k_f4<<<NNODES, 64, 0, stream>>>(0, G0p, G1o1, G1i1, G0L0, G1o0, G1i0,
        row_ptr, csr_src, csr_wo, csr_wi);
    k_f5<<<2*NNODES, 64, 0, stream>>>(0, G1o1, G1i1, G2o1, G2i1,
        G1o0, G1i0, G2o0, G2i0, row_ptr, csr_src, csr_wo, csr_wi);
    k_f6<<<625, 256, 0, stream>>>(0,
        gaL1h[1], whl1[2], bh[1], Z1, h1f, h1h, Wo, bo, out, 0,
        gaL0h, whl0[2], bh[0], Z0, h0f, h0hb[0]);

    // ---- main pipelined loop: iteration s = L1(s) [A] + L0(s+1) [B] ----
    for (int s=0; s<SEQT; ++s){
        const int pr = s & 1;
        const int doB = (s+1 < SEQT) ? 1 : 0;
        const _Float16* xp = Xtph + (size_t)(doB ? s+1 : s)*NB*2;
        k_f1<<<2*NNODES, 64, 0, stream>>>(NNODES,
            h0hb[pr], h1h, T1o64, T1i64, xp, Th1o, Th1i, XTh,
            row_ptr, csr_src, csr_wo, csr_wi);
        k_f2<<<4*NNODES, 64, 0, stream>>>(2*NNODES,
            T1o64, T1i64, U2o64, U2i64,
            Th1o, Th1i, Th2o, Th2i, XTh, row_ptr, csr_src, csr_wo, csr_wi);
        k_f3<<<625*(1+doB), 256, 0, stream>>>(625,
            gaL1zr[pr], whl1[0], bz[1], whl1[1], br[1], Z1, G0p, h1f,
            gaL0zr[pr], whl0[0], bz[0], whl0[1], br[0], Z0, G0L0, h0f);
        k_f4<<<NNODES*(1+doB), 64, 0, stream>>>(NNODES,
            G0p, G1o1, G1i1, G0L0, G1o0, G1i0, row_ptr, csr_src, csr_wo, csr_wi);
        k_f5<<<2*NNODES*(1+doB), 64, 0, stream>>>(2*NNODES,
            G1o1, G1i1, G2o1, G2i1, G1o0, G1i0, G2o0, G2i0,
            row_ptr, csr_src, csr_wo, csr_wi);
        k_f6<<<625*(1+doB), 256, 0, stream>>>(625,
            gaL1h[pr], whl1[2], bh[1], Z1, h1f, h1h, Wo, bo, out, s,
            gaL0h, whl0[2], bh[0], Z0, h0f, h0hb[(s+1)&1]);
    }
}